// Round 7
// baseline (726.436 us; speedup 1.0000x reference)
//
#include <hip/hip_runtime.h>
#include <hip/hip_bf16.h>

#define DM 48
#define NS 21
#define HDm 24
#define ITERS 3
#define NWAVE 12   // 12 waves = 3/SIMD -> VGPR cap 170 (LDS-bound occupancy anyway)
#define NTHR (NWAVE*64)

#define K_ST 60     // K row stride (u16): 120B = 30 dwords -> bank period 16 (scores reads ~2-way)
#define VT_ST 28    // V^T row stride (u16): 56B = 14 dwords -> period 16 with b64 reads (3-way)
#define WKV_ST 56   // wkv rows; col48 = bias, 49-55 = 0
#define WQ_ST 56
#define WHN_ST 56
#define WC_ST 104   // W_cat = [wih@opw | whh] rows
#define P_ST 52

typedef short s16x8 __attribute__((ext_vector_type(8)));
typedef float f32x4 __attribute__((ext_vector_type(4)));
typedef unsigned short u16;

__device__ __forceinline__ u16 f2bu(float f) {
    __hip_bfloat16 h = __float2bfloat16(f);
    return *reinterpret_cast<u16*>(&h);
}
__device__ __forceinline__ float bu2f_lo(unsigned u){ return __uint_as_float(u<<16); }
__device__ __forceinline__ float bu2f_hi(unsigned u){ return __uint_as_float(u & 0xffff0000u); }
__device__ __forceinline__ void w_hilo(u16* hi, u16* lo, int idx, float x) {
    u16 h = f2bu(x);
    hi[idx] = h;
    lo[idx] = f2bu(x - __uint_as_float(((unsigned)h) << 16));
}
#define MFMA(a,b,c) __builtin_amdgcn_mfma_f32_16x16x32_bf16(a,b,c,0,0,0)

// DPP cross-lane (VALU-speed, replaces ds_swizzle for levels <=8 within 16-lane rows)
template<int C>
__device__ __forceinline__ float dppf(float x) {
    return __builtin_bit_cast(float,
        __builtin_amdgcn_update_dpp(0, __builtin_bit_cast(int, x), C, 0xF, 0xF, true));
}
// full reduce over 16-lane row: quad xor1 (0xB1), xor2 (0x4E), half-mirror (0x141), mirror (0x140)
__device__ __forceinline__ float row16_sum(float x) {
    x += dppf<0xB1>(x); x += dppf<0x4E>(x); x += dppf<0x141>(x); x += dppf<0x140>(x);
    return x;
}
__device__ __forceinline__ float row16_max(float x) {
    x = fmaxf(x, dppf<0xB1>(x)); x = fmaxf(x, dppf<0x4E>(x));
    x = fmaxf(x, dppf<0x141>(x)); x = fmaxf(x, dppf<0x140>(x));
    return x;
}

__device__ __forceinline__ void acc8(const float4& a, const float4& b, float& s1, float& s2) {
    s1 += (a.x+a.y)+(a.z+a.w) + (b.x+b.y)+(b.z+b.w);
    s2 += a.x*a.x + a.y*a.y + a.z*a.z + a.w*a.w
        + b.x*b.x + b.y*b.y + b.z*b.z + b.w*b.w;
}
// normalize 8 features and emit bf16 hi/lo B-fragment (all in registers)
__device__ __forceinline__ void frag_hilo(const float4& xa, const float4& xb,
    const float4& ga, const float4& gb, const float4& ba, const float4& bb,
    float mu, float rs, s16x8& h, s16x8& lo)
{
    float x[8] = {xa.x,xa.y,xa.z,xa.w,xb.x,xb.y,xb.z,xb.w};
    float g[8] = {ga.x,ga.y,ga.z,ga.w,gb.x,gb.y,gb.z,gb.w};
    float b[8] = {ba.x,ba.y,ba.z,ba.w,bb.x,bb.y,bb.z,bb.w};
    #pragma unroll
    for (int j = 0; j < 8; ++j) {
        float y = (x[j]-mu)*rs*g[j] + b[j];
        u16 hh = f2bu(y);
        h[j]  = (short)hh;
        lo[j] = (short)f2bu(y - __uint_as_float(((unsigned)hh) << 16));
    }
}

__global__ __launch_bounds__(NTHR, 3) void fusion_kernel(
    const float* __restrict__ slot, const float* __restrict__ fq,
    const float* __restrict__ ipw,  const float* __restrict__ ipb,
    const float* __restrict__ opw,  const float* __restrict__ opb,
    const float* __restrict__ lnqg, const float* __restrict__ lnqb,
    const float* __restrict__ lnkg, const float* __restrict__ lnkb,
    const float* __restrict__ wih,  const float* __restrict__ whh,
    const float* __restrict__ bih,  const float* __restrict__ bhh,
    const float* __restrict__ sigr, const float* __restrict__ praw,
    const float* __restrict__ p1w,  const float* __restrict__ p1b,
    const float* __restrict__ p2w,  const float* __restrict__ p2b,
    float* __restrict__ outp, const int M)
{
    // ---- block-wide weights ----
    __shared__ __align__(16) u16 s_wkv[96*WKV_ST];
    __shared__ __align__(16) u16 s_wq [48*WQ_ST];
    __shared__ __align__(16) u16 s_whn[48*WHN_ST];
    __shared__ __align__(16) u16 s_wcat[144*WC_ST];
    __shared__ __align__(16) u16 s_p1[48*P_ST];
    __shared__ __align__(16) u16 s_p2[48*P_ST];
    __shared__ __align__(16) u16 zblk[8];
    __shared__ float s_bg[144];
    __shared__ __align__(16) float s_lnqg[48], s_lnqb[48];
    __shared__ __align__(16) float s_lnkg[48], s_lnkb[48];
    __shared__ float s_sig[48], s_p1b[48], s_p2b[48], s_fq[48];
    __shared__ float s_pp;
    // ---- per-wave scratch ----
    __shared__ __align__(16) u16   s_K [NWAVE][NS*K_ST];    // K bf16 [slot][48]
    __shared__ __align__(16) u16   s_vt[NWAVE][48*VT_ST];   // V^T bf16 [48][slot]
    __shared__ __align__(16) u16   s_qnh[NWAVE][64];        // LN(q) hi; [48]=1, rest 0
    __shared__ __align__(16) u16   s_qnl[NWAVE][64];        // LN(q) lo
    __shared__ __align__(16) u16   s_xch[NWAVE][112];       // [attn | q | 1 | 0] hi
    __shared__ __align__(16) u16   s_xcl[NWAVE][112];       // lo plane
    __shared__ __align__(16) float s_Qv [NWAVE][48];
    __shared__ __align__(16) float s_aw [NWAVE][64];
    __shared__ __align__(16) float s_g1 [NWAVE][144];
    __shared__ __align__(16) float s_g2 [NWAVE][48];

    const int tid = threadIdx.x;
    for (int i = tid; i < 48*WQ_ST; i += NTHR) {
        int r = i / WQ_ST, c = i - r*WQ_ST;
        s_wq[i] = f2bu(c < 48 ? ipw[r*48+c] : (c == 48 ? ipb[r] : 0.f));
    }
    for (int i = tid; i < 96*WKV_ST; i += NTHR) {
        int r = i / WKV_ST, c = i - r*WKV_ST;
        s_wkv[i] = f2bu(c < 48 ? ipw[(48+r)*48+c] : (c == 48 ? ipb[48+r] : 0.f));
    }
    for (int i = tid; i < 48*WHN_ST; i += NTHR) {
        int r = i / WHN_ST, c = i - r*WHN_ST;
        s_whn[i] = f2bu(c < 48 ? whh[(96+r)*48+c] : (c == 48 ? bhh[96+r] : 0.f));
    }
    for (int i = tid; i < 144*WC_ST; i += NTHR) {
        int r = i / WC_ST, c = i - r*WC_ST;
        float v = 0.f;
        if (c < 48) { float a = 0.f;
            for (int t = 0; t < 48; ++t) a = fmaf(wih[r*48+t], opw[t*48+c], a);
            v = a;
        } else if (c < 96 && r < 96) v = whh[r*48 + (c-48)];
        s_wcat[i] = f2bu(v);
    }
    for (int i = tid; i < 48*P_ST; i += NTHR) {
        int r = i / P_ST, c = i - r*P_ST;
        s_p1[i] = f2bu(c < 48 ? p1w[r*48+c] : 0.f);
        s_p2[i] = f2bu(c < 48 ? p2w[r*48+c] : 0.f);
    }
    if (tid < 144) {
        float a = bih[tid] + (tid < 96 ? bhh[tid] : 0.f);
        for (int t = 0; t < 48; ++t) a = fmaf(wih[tid*48+t], opb[t], a);
        s_bg[tid] = a;
    }
    if (tid < 48) {
        s_lnqg[tid] = lnqg[tid]; s_lnqb[tid] = lnqb[tid];
        s_lnkg[tid] = lnkg[tid]; s_lnkb[tid] = lnkb[tid];
        s_sig[tid] = log1pf(__expf(sigr[tid])) + 0.01f;
        s_p1b[tid] = p1b[tid]; s_p2b[tid] = p2b[tid];
        s_fq[tid] = fq[tid];
    }
    if (tid < 8) zblk[tid] = 0;
    if (tid == 0) s_pp = 1.5f + log1pf(__expf(praw[0]));
    __syncthreads();

    const int w = tid >> 6, l = tid & 63;
    const int jl = (l < DM) ? l : 0;
    const int g = l >> 4, lm = l & 15, g8 = (l >> 4)*8;
    const int kg = g;                         // k-group for B-fragments
    u16* __restrict__ kv  = s_K[w];
    u16* __restrict__ vt  = s_vt[w];
    u16* __restrict__ qnh = s_qnh[w];
    u16* __restrict__ qnl = s_qnl[w];
    u16* __restrict__ xch = s_xch[w];
    u16* __restrict__ xcl = s_xcl[w];
    float* __restrict__ Qv = s_Qv[w];
    float* __restrict__ aw = s_aw[w];
    float* __restrict__ vg1 = s_g1[w];
    float* __restrict__ vg2 = s_g2[w];

    // one-time per-wave inits
    for (int e = l; e < 48*3; e += 64) {      // V^T pad cols 21-23 = 0 (NaN guard, aw=0 kills)
        int r = e / 3;
        vt[r*VT_ST + NS + (e - r*3)] = 0;
    }
    if (l >= 48) { qnh[l] = (l == 48) ? (u16)0x3F80 : (u16)0; qnl[l] = 0; }
    if (l < 16)  { xch[96 + l] = (l == 0) ? (u16)0x3F80 : (u16)0; xcl[96 + l] = 0; }

    const float pexp = s_pp, pinv = 1.0f / s_pp;
    const int h2 = (jl >= HDm) ? 1 : 0;
    const int sh = l >> 5, snn = l & 31;
    const bool sact = snn < NS;
    const int sn = sact ? snn : 0;

    // per-lane feature sets for the K/V GEMM B-fragments (reg-resident kvn):
    // frag0: features kg*8..+7 ; frag1: kg<2 -> features 32+kg*8..+7, kg2 -> bias, kg3 -> 0
    const int n0 = lm;                         // slot for fragment pair 0
    const int n1 = (lm < 5) ? 16 + lm : 20;    // slot for pair 1 (clamped; D discarded)
    const int fo0 = kg*8;
    const int fo1 = 32 + ((kg < 2) ? kg*8 : 0);
    const float4 g0a = *(const float4*)&s_lnkg[fo0];
    const float4 g0b = *(const float4*)&s_lnkg[fo0+4];
    const float4 b0a = *(const float4*)&s_lnkb[fo0];
    const float4 b0b = *(const float4*)&s_lnkb[fo0+4];
    const float4 g1a = *(const float4*)&s_lnkg[fo1];
    const float4 g1b = *(const float4*)&s_lnkg[fo1+4];
    const float4 b1a = *(const float4*)&s_lnkb[fo1];
    const float4 b1b = *(const float4*)&s_lnkb[fo1+4];
    const s16x8 biasf = (s16x8){(short)0x3F80,0,0,0,0,0,0,0};
    const s16x8 zero8 = (s16x8){0,0,0,0,0,0,0,0};

    const int gw0 = blockIdx.x*NWAVE + w;
    const int stride = gridDim.x*NWAVE;

    // software-pipelined row loads: 8 x float4 per lane
    float4 pa0, pa1, pb0, pb1, pc0, pc1, pd0, pd1;
    {
        const float* kp = slot + (size_t)gw0 * (NS*DM);
        const float* q0 = kp + n0*48 + fo0; pa0 = *(const float4*)q0; pa1 = *(const float4*)(q0+4);
        const float* q1 = kp + n0*48 + fo1; pb0 = *(const float4*)q1; pb1 = *(const float4*)(q1+4);
        const float* q2 = kp + n1*48 + fo0; pc0 = *(const float4*)q2; pc1 = *(const float4*)(q2+4);
        const float* q3 = kp + n1*48 + fo1; pd0 = *(const float4*)q3; pd1 = *(const float4*)(q3+4);
    }

    for (int m = gw0; m < M; m += stride) {
        // ---- LN(kv) in registers: in-lane partials + 2 shuffle levels ----
        float s1 = 0.f, s2 = 0.f;
        acc8(pa0, pa1, s1, s2);
        if (kg < 2) acc8(pb0, pb1, s1, s2);
        s1 += __shfl_xor(s1, 16); s2 += __shfl_xor(s2, 16);
        s1 += __shfl_xor(s1, 32); s2 += __shfl_xor(s2, 32);
        float mu0 = s1 * (1.f/48.f);
        float rs0 = rsqrtf(s2 * (1.f/48.f) - mu0*mu0 + 1e-5f);
        float t1 = 0.f, t2 = 0.f;
        acc8(pc0, pc1, t1, t2);
        if (kg < 2) acc8(pd0, pd1, t1, t2);
        t1 += __shfl_xor(t1, 16); t2 += __shfl_xor(t2, 16);
        t1 += __shfl_xor(t1, 32); t2 += __shfl_xor(t2, 32);
        float mu1 = t1 * (1.f/48.f);
        float rs1 = rsqrtf(t2 * (1.f/48.f) - mu1*mu1 + 1e-5f);

        s16x8 F0h, F0l, F1h, F1l, G0h, G0l, G1h, G1l;
        frag_hilo(pa0, pa1, g0a, g0b, b0a, b0b, mu0, rs0, F0h, F0l);
        frag_hilo(pc0, pc1, g0a, g0b, b0a, b0b, mu1, rs1, G0h, G0l);
        if (kg < 2) {
            frag_hilo(pb0, pb1, g1a, g1b, b1a, b1b, mu0, rs0, F1h, F1l);
            frag_hilo(pd0, pd1, g1a, g1b, b1a, b1b, mu1, rs1, G1h, G1l);
        } else if (kg == 2) { F1h = biasf; G1h = biasf; F1l = zero8; G1l = zero8; }
        else                { F1h = zero8; G1h = zero8; F1l = zero8; G1l = zero8; }

        // ---- prefetch next row (hides HBM latency under GEMM + iterations) ----
        {
            int mn = (m + stride < M) ? m + stride : m;
            const float* kp = slot + (size_t)mn * (NS*DM);
            const float* q0 = kp + n0*48 + fo0; pa0 = *(const float4*)q0; pa1 = *(const float4*)(q0+4);
            const float* q1 = kp + n0*48 + fo1; pb0 = *(const float4*)q1; pb1 = *(const float4*)(q1+4);
            const float* q2 = kp + n1*48 + fo0; pc0 = *(const float4*)q2; pc1 = *(const float4*)(q2+4);
            const float* q3 = kp + n1*48 + fo1; pd0 = *(const float4*)q3; pd1 = *(const float4*)(q3+4);
        }

        // ---- K,V via MFMA: A=wkv bf16 (LDS), B=reg-resident kvn hi+lo ----
        #pragma unroll
        for (int mt = 0; mt < 6; ++mt) {
            const u16* ar = &s_wkv[(mt*16 + lm)*WKV_ST];
            s16x8 A0 = *(const s16x8*)&ar[g8];
            s16x8 A1 = (g8 < 24) ? *(const s16x8*)&ar[32 + g8] : *(const s16x8*)zblk;
            #pragma unroll
            for (int nt = 0; nt < 2; ++nt) {
                f32x4 acc = {0.f, 0.f, 0.f, 0.f};
                acc = MFMA(A0, nt ? G0h : F0h, acc);
                acc = MFMA(A1, nt ? G1h : F1h, acc);
                acc = MFMA(A0, nt ? G0l : F0l, acc);
                acc = MFMA(A1, nt ? G1l : F1l, acc);
                int slotn = lm + nt*16;
                if (slotn < NS) {
                    if (mt < 3) {        // K
                        uint2 pk;
                        pk.x = (unsigned)f2bu(acc[0]) | ((unsigned)f2bu(acc[1]) << 16);
                        pk.y = (unsigned)f2bu(acc[2]) | ((unsigned)f2bu(acc[3]) << 16);
                        *(uint2*)&kv[slotn*K_ST + mt*16 + g*4] = pk;
                    } else {             // V transposed
                        int ch = (mt-3)*16 + g*4;
                        vt[(ch+0)*VT_ST + slotn] = f2bu(acc[0]);
                        vt[(ch+1)*VT_ST + slotn] = f2bu(acc[1]);
                        vt[(ch+2)*VT_ST + slotn] = f2bu(acc[2]);
                        vt[(ch+3)*VT_ST + slotn] = f2bu(acc[3]);
                    }
                }
            }
        }

        // ---- 3 GRU-attention iterations ----
        float qreg = s_fq[jl];
        if (l < DM) w_hilo(xch, xcl, 48 + l, qreg);
        #pragma unroll 1
        for (int it = 0; it < ITERS; ++it) {
            // LN(q): DPP levels 1-8, DS shuffles only for 16/32
            float xq = (l < DM) ? qreg : 0.f;
            float q1s = row16_sum(xq);
            float q2s = row16_sum(xq*xq);
            q1s += __shfl_xor(q1s, 16); q2s += __shfl_xor(q2s, 16);
            q1s += __shfl_xor(q1s, 32); q2s += __shfl_xor(q2s, 32);
            float mu = q1s * (1.f/48.f);
            float rs = rsqrtf(q2s * (1.f/48.f) - mu*mu + 1e-5f);
            if (l < DM) w_hilo(qnh, qnl, l, (xq - mu)*rs*s_lnqg[jl] + s_lnqb[jl]);
            // Q = MFMA(wq, qn hi+lo)
            s16x8 Bq0h = *(const s16x8*)&qnh[g8];
            s16x8 Bq1h = *(const s16x8*)&qnh[32 + g8];
            s16x8 Bq0l = *(const s16x8*)&qnl[g8];
            s16x8 Bq1l = *(const s16x8*)&qnl[32 + g8];
            #pragma unroll
            for (int mt = 0; mt < 3; ++mt) {
                const u16* ar = &s_wq[(mt*16 + lm)*WQ_ST];
                s16x8 A0 = *(const s16x8*)&ar[g8];
                s16x8 A1 = (g8 < 24) ? *(const s16x8*)&ar[32 + g8] : *(const s16x8*)zblk;
                f32x4 acc = {0.f, 0.f, 0.f, 0.f};
                acc = MFMA(A0, Bq0h, acc);
                acc = MFMA(A1, Bq1h, acc);
                acc = MFMA(A0, Bq0l, acc);
                acc = MFMA(A1, Bq1l, acc);
                if (lm == 0) *(f32x4*)&Qv[mt*16 + g*4] = acc;
            }
            // scores + softmax (lane = head*32 + slot); DPP reduce + 1 shuffle
            float dt = 0.f;
            #pragma unroll
            for (int d4 = 0; d4 < 6; ++d4) {
                float4 q4 = *(const float4*)&Qv[sh*HDm + d4*4];
                uint2 ku = *(const uint2*)&kv[sn*K_ST + sh*HDm + d4*4];
                dt = fmaf(q4.x, bu2f_lo(ku.x), dt);
                dt = fmaf(q4.y, bu2f_hi(ku.x), dt);
                dt = fmaf(q4.z, bu2f_lo(ku.y), dt);
                dt = fmaf(q4.w, bu2f_hi(ku.y), dt);
            }
            float sc = sact ? dt * 0.20412414523193154f : -3.0e38f;
            float mx = row16_max(sc);
            mx = fmaxf(mx, __shfl_xor(mx, 16));
            float ex = __expf(sc - mx);
            float se = row16_sum(ex);
            se += __shfl_xor(se, 16);
            aw[l] = ex / se;                   // lanes snn>=21 -> exactly 0
            // attn via V^T (b64 reads, stride 28 -> ~3-way conflicts)
            float at = 0.f;
            #pragma unroll
            for (int b = 0; b < 6; ++b) {
                uint2 vv = *(const uint2*)&vt[jl*VT_ST + b*4];
                const float* ap = &aw[h2*32 + b*4];
                float2 a0 = *(const float2*)(ap + 0);
                float2 a1 = *(const float2*)(ap + 2);
                at = fmaf(a0.x, bu2f_lo(vv.x), at);
                at = fmaf(a0.y, bu2f_hi(vv.x), at);
                at = fmaf(a1.x, bu2f_lo(vv.y), at);
                at = fmaf(a1.y, bu2f_hi(vv.y), at);
            }
            if (l < DM) w_hilo(xch, xcl, l, at);
            // GRU GEMMs (unchanged)
            s16x8 Bc0h = *(const s16x8*)&xch[g8];
            s16x8 Bc1h = *(const s16x8*)&xch[32 + g8];
            s16x8 Bc2h = *(const s16x8*)&xch[64 + g8];
            s16x8 Bc0l = *(const s16x8*)&xcl[g8];
            s16x8 Bc1l = *(const s16x8*)&xcl[32 + g8];
            s16x8 Bc2l = *(const s16x8*)&xcl[64 + g8];
            #pragma unroll 3
            for (int mt = 0; mt < 9; ++mt) {
                const u16* ar = &s_wcat[(mt*16 + lm)*WC_ST];
                s16x8 A0 = *(const s16x8*)&ar[g8];
                s16x8 A1 = *(const s16x8*)&ar[32 + g8];
                f32x4 acc = {0.f, 0.f, 0.f, 0.f};
                acc = MFMA(A0, Bc0h, acc);
                acc = MFMA(A1, Bc1h, acc);
                acc = MFMA(A0, Bc0l, acc);
                acc = MFMA(A1, Bc1l, acc);
                if (mt < 6) {
                    s16x8 A2 = *(const s16x8*)&ar[64 + g8];
                    acc = MFMA(A2, Bc2h, acc);
                    acc = MFMA(A2, Bc2l, acc);
                }
                if (lm == 0) *(f32x4*)&vg1[mt*16 + g*4] = acc;
            }
            s16x8 Bh0h = *(const s16x8*)&xch[48 + g8];
            s16x8 Bh1h = *(const s16x8*)&xch[80 + g8];
            s16x8 Bh0l = *(const s16x8*)&xcl[48 + g8];
            s16x8 Bh1l = *(const s16x8*)&xcl[80 + g8];
            #pragma unroll
            for (int mt = 0; mt < 3; ++mt) {
                const u16* ar = &s_whn[(mt*16 + lm)*WHN_ST];
                s16x8 A0 = *(const s16x8*)&ar[g8];
                s16x8 A1 = (g8 < 24) ? *(const s16x8*)&ar[32 + g8] : *(const s16x8*)zblk;
                f32x4 acc = {0.f, 0.f, 0.f, 0.f};
                acc = MFMA(A0, Bh0h, acc);
                acc = MFMA(A1, Bh1h, acc);
                acc = MFMA(A0, Bh0l, acc);
                acc = MFMA(A1, Bh1l, acc);
                if (lm == 0) *(f32x4*)&vg2[mt*16 + g*4] = acc;
            }
            float yr = vg1[jl]      + s_bg[jl];
            float yz = vg1[48 + jl] + s_bg[48 + jl];
            float yn = vg1[96 + jl] + s_bg[96 + jl];
            float hn = vg2[jl];
            float r = 1.f / (1.f + __expf(-yr));
            float z = 1.f / (1.f + __expf(-yz));
            float nn = tanhf(yn + r*hn);
            qreg = (1.f - z)*nn + z*qreg;
            if (l < DM) w_hilo(xch, xcl, 48 + l, qreg);
        }

        // ---- outputs ----
        if (l < NS)
            outp[(size_t)M*DM + (size_t)m*NS + l] = 0.5f*(aw[l] + aw[32 + l]);
        float f = qreg;
        float ratio = fminf(fabsf(f) / s_sig[jl], 15.f);
        float rp = __powf(ratio, pexp);
        f = f / __powf(1.f + rp, pinv);
        if (l < DM) Qv[l] = f;      // Qv reused as tail vx (Q dead)
        float4 a4 = {0,0,0,0};
        #pragma unroll
        for (int d4 = 0; d4 < 12; ++d4) {
            uint2 rw = *(const uint2*)&s_p1[jl*P_ST + d4*4];
            float4 x4 = *(const float4*)&Qv[d4*4];
            a4.x = fmaf(bu2f_lo(rw.x), x4.x, a4.x);
            a4.y = fmaf(bu2f_hi(rw.x), x4.y, a4.y);
            a4.z = fmaf(bu2f_lo(rw.y), x4.z, a4.z);
            a4.w = fmaf(bu2f_hi(rw.y), x4.w, a4.w);
        }
        float h1 = fmaxf(0.f, s_p1b[jl] + (a4.x + a4.y) + (a4.z + a4.w));
        if (l < DM) Qv[l] = h1;
        float4 c4 = {0,0,0,0};
        #pragma unroll
        for (int d4 = 0; d4 < 12; ++d4) {
            uint2 rw = *(const uint2*)&s_p2[jl*P_ST + d4*4];
            float4 x4 = *(const float4*)&Qv[d4*4];
            c4.x = fmaf(bu2f_lo(rw.x), x4.x, c4.x);
            c4.y = fmaf(bu2f_hi(rw.x), x4.y, c4.y);
            c4.z = fmaf(bu2f_lo(rw.y), x4.z, c4.z);
            c4.w = fmaf(bu2f_hi(rw.y), x4.w, c4.w);
        }
        if (l < DM) outp[(size_t)m*DM + l] = s_p2b[jl] + (c4.x + c4.y) + (c4.z + c4.w);
    }
}

extern "C" void kernel_launch(void* const* d_in, const int* in_sizes, int n_in,
                              void* d_out, int out_size, void* d_ws, size_t ws_size,
                              hipStream_t stream) {
    const float* slot = (const float*)d_in[0];
    const float* fq   = (const float*)d_in[1];
    const float* ipw  = (const float*)d_in[2];
    const float* ipb  = (const float*)d_in[3];
    const float* opw  = (const float*)d_in[4];
    const float* opb  = (const float*)d_in[5];
    const float* lnqg = (const float*)d_in[6];
    const float* lnqb = (const float*)d_in[7];
    const float* lnkg = (const float*)d_in[8];
    const float* lnkb = (const float*)d_in[9];
    const float* wih  = (const float*)d_in[10];
    const float* whh  = (const float*)d_in[11];
    const float* bihp = (const float*)d_in[12];
    const float* bhhp = (const float*)d_in[13];
    const float* sigr = (const float*)d_in[14];
    const float* praw = (const float*)d_in[15];
    const float* p1w  = (const float*)d_in[16];
    const float* p1b  = (const float*)d_in[17];
    const float* p2w  = (const float*)d_in[18];
    const float* p2b  = (const float*)d_in[19];
    const int M = in_sizes[0] / (NS*DM);   // 65536
    fusion_kernel<<<dim3(256), dim3(NTHR), 0, stream>>>(
        slot, fq, ipw, ipb, opw, opb, lnqg, lnqb, lnkg, lnkb,
        wih, whh, bihp, bhhp, sigr, praw, p1w, p1b, p2w, p2b,
        (float*)d_out, M);
}

// Round 8
// 664.628 us; speedup vs baseline: 1.0930x; 1.0930x over previous
//
#include <hip/hip_runtime.h>
#include <hip/hip_bf16.h>

#define DM 48
#define NS 21
#define HDm 24
#define ITERS 3
#define NWAVE 12   // 12 waves = 3/SIMD
#define NTHR (NWAVE*64)

#define K_ST 60    // K row stride (u16)
#define VT_ST 28   // V^T row stride (u16)
#define WKV_ST 56  // wkv rows; col48 = bias, 49-55 = 0
#define WQ_ST 56
#define WHN_ST 56
#define WC_ST 104  // W_cat = [wih@opw | whh] rows
#define P_ST 52

typedef short s16x8 __attribute__((ext_vector_type(8)));
typedef float f32x4 __attribute__((ext_vector_type(4)));
typedef unsigned short u16;

__device__ __forceinline__ u16 f2bu(float f) {
    __hip_bfloat16 h = __float2bfloat16(f);
    return *reinterpret_cast<u16*>(&h);
}
__device__ __forceinline__ float bu2f_lo(unsigned u){ return __uint_as_float(u<<16); }
__device__ __forceinline__ float bu2f_hi(unsigned u){ return __uint_as_float(u & 0xffff0000u); }
__device__ __forceinline__ void w_hilo(u16* hi, u16* lo, int idx, float x) {
    u16 h = f2bu(x);
    hi[idx] = h;
    lo[idx] = f2bu(x - __uint_as_float(((unsigned)h) << 16));
}
#define MFMA(a,b,c) __builtin_amdgcn_mfma_f32_16x16x32_bf16(a,b,c,0,0,0)

// DPP cross-lane (VALU-speed) for reduction levels <=8 within 16-lane rows
template<int C>
__device__ __forceinline__ float dppf(float x) {
    return __builtin_bit_cast(float,
        __builtin_amdgcn_update_dpp(0, __builtin_bit_cast(int, x), C, 0xF, 0xF, true));
}
__device__ __forceinline__ float row16_sum(float x) {
    x += dppf<0xB1>(x); x += dppf<0x4E>(x); x += dppf<0x141>(x); x += dppf<0x140>(x);
    return x;
}
__device__ __forceinline__ float row16_max(float x) {
    x = fmaxf(x, dppf<0xB1>(x)); x = fmaxf(x, dppf<0x4E>(x));
    x = fmaxf(x, dppf<0x141>(x)); x = fmaxf(x, dppf<0x140>(x));
    return x;
}

__device__ __forceinline__ void acc8(const float4& a, const float4& b, float& s1, float& s2) {
    s1 += (a.x+a.y)+(a.z+a.w) + (b.x+b.y)+(b.z+b.w);
    s2 += a.x*a.x + a.y*a.y + a.z*a.z + a.w*a.w
        + b.x*b.x + b.y*b.y + b.z*b.z + b.w*b.w;
}
__device__ __forceinline__ void frag_hilo(const float4& xa, const float4& xb,
    const float4& ga, const float4& gb, const float4& ba, const float4& bb,
    float mu, float rs, s16x8& h, s16x8& lo)
{
    float x[8] = {xa.x,xa.y,xa.z,xa.w,xb.x,xb.y,xb.z,xb.w};
    float g[8] = {ga.x,ga.y,ga.z,ga.w,gb.x,gb.y,gb.z,gb.w};
    float b[8] = {ba.x,ba.y,ba.z,ba.w,bb.x,bb.y,bb.z,bb.w};
    #pragma unroll
    for (int j = 0; j < 8; ++j) {
        float y = (x[j]-mu)*rs*g[j] + b[j];
        u16 hh = f2bu(y);
        h[j]  = (short)hh;
        lo[j] = (short)f2bu(y - __uint_as_float(((unsigned)hh) << 16));
    }
}

__global__ __launch_bounds__(NTHR, 3) void fusion_kernel(
    const float* __restrict__ slot, const float* __restrict__ fq,
    const float* __restrict__ ipw,  const float* __restrict__ ipb,
    const float* __restrict__ opw,  const float* __restrict__ opb,
    const float* __restrict__ lnqg, const float* __restrict__ lnqb,
    const float* __restrict__ lnkg, const float* __restrict__ lnkb,
    const float* __restrict__ wih,  const float* __restrict__ whh,
    const float* __restrict__ bih,  const float* __restrict__ bhh,
    const float* __restrict__ sigr, const float* __restrict__ praw,
    const float* __restrict__ p1w,  const float* __restrict__ p1b,
    const float* __restrict__ p2w,  const float* __restrict__ p2b,
    float* __restrict__ outp, const int M)
{
    // ---- block-wide weights ----
    __shared__ __align__(16) u16 s_wkv[96*WKV_ST];
    __shared__ __align__(16) u16 s_wq [48*WQ_ST];
    __shared__ __align__(16) u16 s_whn[48*WHN_ST];
    __shared__ __align__(16) u16 s_wcat[144*WC_ST];
    __shared__ __align__(16) u16 s_p1[48*P_ST];
    __shared__ __align__(16) u16 s_p2[48*P_ST];
    __shared__ __align__(16) u16 zblk[8];
    __shared__ float s_bg[144];
    __shared__ __align__(16) float s_lnqg[48], s_lnqb[48];
    __shared__ __align__(16) float s_lnkg[48], s_lnkb[48];
    __shared__ float s_sig[48], s_p1b[48], s_p2b[48], s_fq[48];
    __shared__ float s_pp;
    // ---- per-wave scratch ----
    __shared__ __align__(16) u16   s_K [NWAVE][NS*K_ST];
    __shared__ __align__(16) u16   s_vt[NWAVE][48*VT_ST];
    __shared__ __align__(16) u16   s_qnh[NWAVE][64];
    __shared__ __align__(16) u16   s_qnl[NWAVE][64];
    __shared__ __align__(16) u16   s_xch[NWAVE][112];
    __shared__ __align__(16) u16   s_xcl[NWAVE][112];
    __shared__ __align__(16) float s_Qv [NWAVE][48];
    __shared__ __align__(16) float s_aw [NWAVE][64];
    __shared__ __align__(16) float s_g1 [NWAVE][144];
    __shared__ __align__(16) float s_g2 [NWAVE][48];

    const int tid = threadIdx.x;
    for (int i = tid; i < 48*WQ_ST; i += NTHR) {
        int r = i / WQ_ST, c = i - r*WQ_ST;
        s_wq[i] = f2bu(c < 48 ? ipw[r*48+c] : (c == 48 ? ipb[r] : 0.f));
    }
    for (int i = tid; i < 96*WKV_ST; i += NTHR) {
        int r = i / WKV_ST, c = i - r*WKV_ST;
        s_wkv[i] = f2bu(c < 48 ? ipw[(48+r)*48+c] : (c == 48 ? ipb[48+r] : 0.f));
    }
    for (int i = tid; i < 48*WHN_ST; i += NTHR) {
        int r = i / WHN_ST, c = i - r*WHN_ST;
        s_whn[i] = f2bu(c < 48 ? whh[(96+r)*48+c] : (c == 48 ? bhh[96+r] : 0.f));
    }
    for (int i = tid; i < 144*WC_ST; i += NTHR) {
        int r = i / WC_ST, c = i - r*WC_ST;
        float v = 0.f;
        if (c < 48) { float a = 0.f;
            for (int t = 0; t < 48; ++t) a = fmaf(wih[r*48+t], opw[t*48+c], a);
            v = a;
        } else if (c < 96 && r < 96) v = whh[r*48 + (c-48)];
        s_wcat[i] = f2bu(v);
    }
    for (int i = tid; i < 48*P_ST; i += NTHR) {
        int r = i / P_ST, c = i - r*P_ST;
        s_p1[i] = f2bu(c < 48 ? p1w[r*48+c] : 0.f);
        s_p2[i] = f2bu(c < 48 ? p2w[r*48+c] : 0.f);
    }
    if (tid < 144) {
        float a = bih[tid] + (tid < 96 ? bhh[tid] : 0.f);
        for (int t = 0; t < 48; ++t) a = fmaf(wih[tid*48+t], opb[t], a);
        s_bg[tid] = a;
    }
    if (tid < 48) {
        s_lnqg[tid] = lnqg[tid]; s_lnqb[tid] = lnqb[tid];
        s_lnkg[tid] = lnkg[tid]; s_lnkb[tid] = lnkb[tid];
        s_sig[tid] = log1pf(__expf(sigr[tid])) + 0.01f;
        s_p1b[tid] = p1b[tid]; s_p2b[tid] = p2b[tid];
        s_fq[tid] = fq[tid];
    }
    if (tid < 8) zblk[tid] = 0;
    if (tid == 0) s_pp = 1.5f + log1pf(__expf(praw[0]));
    __syncthreads();

    const int w = tid >> 6, l = tid & 63;
    const int jl = (l < DM) ? l : 0;
    const int g = l >> 4, lm = l & 15, g8 = (l >> 4)*8;
    const int kg = g;
    u16* __restrict__ kv  = s_K[w];
    u16* __restrict__ vt  = s_vt[w];
    u16* __restrict__ qnh = s_qnh[w];
    u16* __restrict__ qnl = s_qnl[w];
    u16* __restrict__ xch = s_xch[w];
    u16* __restrict__ xcl = s_xcl[w];
    float* __restrict__ Qv = s_Qv[w];
    float* __restrict__ aw = s_aw[w];
    float* __restrict__ vg1 = s_g1[w];
    float* __restrict__ vg2 = s_g2[w];

    for (int e = l; e < 48*3; e += 64) {      // V^T pad cols 21-23 = 0
        int r = e / 3;
        vt[r*VT_ST + NS + (e - r*3)] = 0;
    }
    if (l >= 48) { qnh[l] = (l == 48) ? (u16)0x3F80 : (u16)0; qnl[l] = 0; }
    if (l < 16)  { xch[96 + l] = (l == 0) ? (u16)0x3F80 : (u16)0; xcl[96 + l] = 0; }

    const float pexp = s_pp, pinv = 1.0f / s_pp;
    const int h2 = (jl >= HDm) ? 1 : 0;
    const int sh = l >> 5, snn = l & 31;
    const bool sact = snn < NS;
    const int sn = sact ? snn : 0;

    // per-lane feature sets for reg-resident kvn B-fragments
    const int n0 = lm;
    const int n1 = (lm < 5) ? 16 + lm : 20;    // clamped; D discarded
    const int fo0 = kg*8;
    const int fo1 = 32 + ((kg < 2) ? kg*8 : 0);
    const float4 g0a = *(const float4*)&s_lnkg[fo0];
    const float4 g0b = *(const float4*)&s_lnkg[fo0+4];
    const float4 b0a = *(const float4*)&s_lnkb[fo0];
    const float4 b0b = *(const float4*)&s_lnkb[fo0+4];
    const float4 g1a = *(const float4*)&s_lnkg[fo1];
    const float4 g1b = *(const float4*)&s_lnkg[fo1+4];
    const float4 b1a = *(const float4*)&s_lnkb[fo1];
    const float4 b1b = *(const float4*)&s_lnkb[fo1+4];
    const s16x8 biasf = (s16x8){(short)0x3F80,0,0,0,0,0,0,0};
    const s16x8 zero8 = (s16x8){0,0,0,0,0,0,0,0};

    const int gw0 = blockIdx.x*NWAVE + w;
    const int stride = gridDim.x*NWAVE;

    // row regs: loaded in preamble / refreshed at END of each row (tail-only liveness
    // -> no spill at the GRU pressure peak; r7 held these across the whole body = spill)
    float4 pa0, pa1, pb0, pb1, pc0, pc1, pd0, pd1;
    {
        const float* kp = slot + (size_t)gw0 * (NS*DM);
        const float* q0 = kp + n0*48 + fo0; pa0 = *(const float4*)q0; pa1 = *(const float4*)(q0+4);
        const float* q1 = kp + n0*48 + fo1; pb0 = *(const float4*)q1; pb1 = *(const float4*)(q1+4);
        const float* q2 = kp + n1*48 + fo0; pc0 = *(const float4*)q2; pc1 = *(const float4*)(q2+4);
        const float* q3 = kp + n1*48 + fo1; pd0 = *(const float4*)q3; pd1 = *(const float4*)(q3+4);
    }

    for (int m = gw0; m < M; m += stride) {
        // ---- LN(kv) in registers: in-lane partials + 2 shuffle levels ----
        float s1 = 0.f, s2 = 0.f;
        acc8(pa0, pa1, s1, s2);
        if (kg < 2) acc8(pb0, pb1, s1, s2);
        s1 += __shfl_xor(s1, 16); s2 += __shfl_xor(s2, 16);
        s1 += __shfl_xor(s1, 32); s2 += __shfl_xor(s2, 32);
        float mu0 = s1 * (1.f/48.f);
        float rs0 = rsqrtf(s2 * (1.f/48.f) - mu0*mu0 + 1e-5f);
        float t1 = 0.f, t2 = 0.f;
        acc8(pc0, pc1, t1, t2);
        if (kg < 2) acc8(pd0, pd1, t1, t2);
        t1 += __shfl_xor(t1, 16); t2 += __shfl_xor(t2, 16);
        t1 += __shfl_xor(t1, 32); t2 += __shfl_xor(t2, 32);
        float mu1 = t1 * (1.f/48.f);
        float rs1 = rsqrtf(t2 * (1.f/48.f) - mu1*mu1 + 1e-5f);

        s16x8 F0h, F0l, F1h, F1l, G0h, G0l, G1h, G1l;
        frag_hilo(pa0, pa1, g0a, g0b, b0a, b0b, mu0, rs0, F0h, F0l);
        frag_hilo(pc0, pc1, g0a, g0b, b0a, b0b, mu1, rs1, G0h, G0l);
        if (kg < 2) {
            frag_hilo(pb0, pb1, g1a, g1b, b1a, b1b, mu0, rs0, F1h, F1l);
            frag_hilo(pd0, pd1, g1a, g1b, b1a, b1b, mu1, rs1, G1h, G1l);
        } else if (kg == 2) { F1h = biasf; G1h = biasf; F1l = zero8; G1l = zero8; }
        else                { F1h = zero8; G1h = zero8; F1l = zero8; G1l = zero8; }

        // ---- K,V via MFMA: A=wkv bf16 (LDS), B=reg-resident kvn hi+lo ----
        #pragma unroll
        for (int mt = 0; mt < 6; ++mt) {
            const u16* ar = &s_wkv[(mt*16 + lm)*WKV_ST];
            s16x8 A0 = *(const s16x8*)&ar[g8];
            s16x8 A1 = (g8 < 24) ? *(const s16x8*)&ar[32 + g8] : *(const s16x8*)zblk;
            #pragma unroll
            for (int nt = 0; nt < 2; ++nt) {
                f32x4 acc = {0.f, 0.f, 0.f, 0.f};
                acc = MFMA(A0, nt ? G0h : F0h, acc);
                acc = MFMA(A1, nt ? G1h : F1h, acc);
                acc = MFMA(A0, nt ? G0l : F0l, acc);
                acc = MFMA(A1, nt ? G1l : F1l, acc);
                int slotn = lm + nt*16;
                if (slotn < NS) {
                    if (mt < 3) {
                        uint2 pk;
                        pk.x = (unsigned)f2bu(acc[0]) | ((unsigned)f2bu(acc[1]) << 16);
                        pk.y = (unsigned)f2bu(acc[2]) | ((unsigned)f2bu(acc[3]) << 16);
                        *(uint2*)&kv[slotn*K_ST + mt*16 + g*4] = pk;
                    } else {
                        int ch = (mt-3)*16 + g*4;
                        vt[(ch+0)*VT_ST + slotn] = f2bu(acc[0]);
                        vt[(ch+1)*VT_ST + slotn] = f2bu(acc[1]);
                        vt[(ch+2)*VT_ST + slotn] = f2bu(acc[2]);
                        vt[(ch+3)*VT_ST + slotn] = f2bu(acc[3]);
                    }
                }
            }
        }

        // ---- 3 GRU-attention iterations ----
        float qreg = s_fq[jl];
        if (l < DM) w_hilo(xch, xcl, 48 + l, qreg);
        #pragma unroll 1
        for (int it = 0; it < ITERS; ++it) {
            // LN(q): DPP levels 1-8, shuffles for 16/32
            float xq = (l < DM) ? qreg : 0.f;
            float q1s = row16_sum(xq);
            float q2s = row16_sum(xq*xq);
            q1s += __shfl_xor(q1s, 16); q2s += __shfl_xor(q2s, 16);
            q1s += __shfl_xor(q1s, 32); q2s += __shfl_xor(q2s, 32);
            float mu = q1s * (1.f/48.f);
            float rs = rsqrtf(q2s * (1.f/48.f) - mu*mu + 1e-5f);
            if (l < DM) w_hilo(qnh, qnl, l, (xq - mu)*rs*s_lnqg[jl] + s_lnqb[jl]);
            // Q = MFMA(wq, qn hi+lo)
            s16x8 Bq0h = *(const s16x8*)&qnh[g8];
            s16x8 Bq1h = *(const s16x8*)&qnh[32 + g8];
            s16x8 Bq0l = *(const s16x8*)&qnl[g8];
            s16x8 Bq1l = *(const s16x8*)&qnl[32 + g8];
            #pragma unroll
            for (int mt = 0; mt < 3; ++mt) {
                const u16* ar = &s_wq[(mt*16 + lm)*WQ_ST];
                s16x8 A0 = *(const s16x8*)&ar[g8];
                s16x8 A1 = (g8 < 24) ? *(const s16x8*)&ar[32 + g8] : *(const s16x8*)zblk;
                f32x4 acc = {0.f, 0.f, 0.f, 0.f};
                acc = MFMA(A0, Bq0h, acc);
                acc = MFMA(A1, Bq1h, acc);
                acc = MFMA(A0, Bq0l, acc);
                acc = MFMA(A1, Bq1l, acc);
                if (lm == 0) *(f32x4*)&Qv[mt*16 + g*4] = acc;
            }
            // scores + softmax
            float dt = 0.f;
            #pragma unroll
            for (int d4 = 0; d4 < 6; ++d4) {
                float4 q4 = *(const float4*)&Qv[sh*HDm + d4*4];
                uint2 ku = *(const uint2*)&kv[sn*K_ST + sh*HDm + d4*4];
                dt = fmaf(q4.x, bu2f_lo(ku.x), dt);
                dt = fmaf(q4.y, bu2f_hi(ku.x), dt);
                dt = fmaf(q4.z, bu2f_lo(ku.y), dt);
                dt = fmaf(q4.w, bu2f_hi(ku.y), dt);
            }
            float sc = sact ? dt * 0.20412414523193154f : -3.0e38f;
            float mx = row16_max(sc);
            mx = fmaxf(mx, __shfl_xor(mx, 16));
            float ex = __expf(sc - mx);
            float se = row16_sum(ex);
            se += __shfl_xor(se, 16);
            aw[l] = ex / se;
            // attn via V^T
            float at = 0.f;
            #pragma unroll
            for (int b = 0; b < 6; ++b) {
                uint2 vv = *(const uint2*)&vt[jl*VT_ST + b*4];
                const float* ap = &aw[h2*32 + b*4];
                float2 a0 = *(const float2*)(ap + 0);
                float2 a1 = *(const float2*)(ap + 2);
                at = fmaf(a0.x, bu2f_lo(vv.x), at);
                at = fmaf(a0.y, bu2f_hi(vv.x), at);
                at = fmaf(a1.x, bu2f_lo(vv.y), at);
                at = fmaf(a1.y, bu2f_hi(vv.y), at);
            }
            if (l < DM) w_hilo(xch, xcl, l, at);
            // GRU GEMMs
            s16x8 Bc0h = *(const s16x8*)&xch[g8];
            s16x8 Bc1h = *(const s16x8*)&xch[32 + g8];
            s16x8 Bc2h = *(const s16x8*)&xch[64 + g8];
            s16x8 Bc0l = *(const s16x8*)&xcl[g8];
            s16x8 Bc1l = *(const s16x8*)&xcl[32 + g8];
            s16x8 Bc2l = *(const s16x8*)&xcl[64 + g8];
            #pragma unroll 3
            for (int mt = 0; mt < 9; ++mt) {
                const u16* ar = &s_wcat[(mt*16 + lm)*WC_ST];
                s16x8 A0 = *(const s16x8*)&ar[g8];
                s16x8 A1 = *(const s16x8*)&ar[32 + g8];
                f32x4 acc = {0.f, 0.f, 0.f, 0.f};
                acc = MFMA(A0, Bc0h, acc);
                acc = MFMA(A1, Bc1h, acc);
                acc = MFMA(A0, Bc0l, acc);
                acc = MFMA(A1, Bc1l, acc);
                if (mt < 6) {
                    s16x8 A2 = *(const s16x8*)&ar[64 + g8];
                    acc = MFMA(A2, Bc2h, acc);
                    acc = MFMA(A2, Bc2l, acc);
                }
                if (lm == 0) *(f32x4*)&vg1[mt*16 + g*4] = acc;
            }
            s16x8 Bh0h = *(const s16x8*)&xch[48 + g8];
            s16x8 Bh1h = *(const s16x8*)&xch[80 + g8];
            s16x8 Bh0l = *(const s16x8*)&xcl[48 + g8];
            s16x8 Bh1l = *(const s16x8*)&xcl[80 + g8];
            #pragma unroll
            for (int mt = 0; mt < 3; ++mt) {
                const u16* ar = &s_whn[(mt*16 + lm)*WHN_ST];
                s16x8 A0 = *(const s16x8*)&ar[g8];
                s16x8 A1 = (g8 < 24) ? *(const s16x8*)&ar[32 + g8] : *(const s16x8*)zblk;
                f32x4 acc = {0.f, 0.f, 0.f, 0.f};
                acc = MFMA(A0, Bh0h, acc);
                acc = MFMA(A1, Bh1h, acc);
                acc = MFMA(A0, Bh0l, acc);
                acc = MFMA(A1, Bh1l, acc);
                if (lm == 0) *(f32x4*)&vg2[mt*16 + g*4] = acc;
            }
            float yr = vg1[jl]      + s_bg[jl];
            float yz = vg1[48 + jl] + s_bg[48 + jl];
            float yn = vg1[96 + jl] + s_bg[96 + jl];
            float hn = vg2[jl];
            float r = 1.f / (1.f + __expf(-yr));
            float z = 1.f / (1.f + __expf(-yz));
            float nn = tanhf(yn + r*hn);
            qreg = (1.f - z)*nn + z*qreg;
            if (l < DM) w_hilo(xch, xcl, 48 + l, qreg);
        }

        // ---- prefetch next row HERE: liveness = tail only (~400cyc) + next LN ----
        {
            int mn = (m + stride < M) ? m + stride : m;
            const float* kp = slot + (size_t)mn * (NS*DM);
            const float* q0 = kp + n0*48 + fo0; pa0 = *(const float4*)q0; pa1 = *(const float4*)(q0+4);
            const float* q1 = kp + n0*48 + fo1; pb0 = *(const float4*)q1; pb1 = *(const float4*)(q1+4);
            const float* q2 = kp + n1*48 + fo0; pc0 = *(const float4*)q2; pc1 = *(const float4*)(q2+4);
            const float* q3 = kp + n1*48 + fo1; pd0 = *(const float4*)q3; pd1 = *(const float4*)(q3+4);
        }

        // ---- outputs ----
        if (l < NS)
            outp[(size_t)M*DM + (size_t)m*NS + l] = 0.5f*(aw[l] + aw[32 + l]);
        float f = qreg;
        float ratio = fminf(fabsf(f) / s_sig[jl], 15.f);
        float rp = __powf(ratio, pexp);
        f = f / __powf(1.f + rp, pinv);
        if (l < DM) Qv[l] = f;
        float4 a4 = {0,0,0,0};
        #pragma unroll
        for (int d4 = 0; d4 < 12; ++d4) {
            uint2 rw = *(const uint2*)&s_p1[jl*P_ST + d4*4];
            float4 x4 = *(const float4*)&Qv[d4*4];
            a4.x = fmaf(bu2f_lo(rw.x), x4.x, a4.x);
            a4.y = fmaf(bu2f_hi(rw.x), x4.y, a4.y);
            a4.z = fmaf(bu2f_lo(rw.y), x4.z, a4.z);
            a4.w = fmaf(bu2f_hi(rw.y), x4.w, a4.w);
        }
        float h1 = fmaxf(0.f, s_p1b[jl] + (a4.x + a4.y) + (a4.z + a4.w));
        if (l < DM) Qv[l] = h1;
        float4 c4 = {0,0,0,0};
        #pragma unroll
        for (int d4 = 0; d4 < 12; ++d4) {
            uint2 rw = *(const uint2*)&s_p2[jl*P_ST + d4*4];
            float4 x4 = *(const float4*)&Qv[d4*4];
            c4.x = fmaf(bu2f_lo(rw.x), x4.x, c4.x);
            c4.y = fmaf(bu2f_hi(rw.x), x4.y, c4.y);
            c4.z = fmaf(bu2f_lo(rw.y), x4.z, c4.z);
            c4.w = fmaf(bu2f_hi(rw.y), x4.w, c4.w);
        }
        if (l < DM) outp[(size_t)m*DM + l] = s_p2b[jl] + (c4.x + c4.y) + (c4.z + c4.w);
    }
}

extern "C" void kernel_launch(void* const* d_in, const int* in_sizes, int n_in,
                              void* d_out, int out_size, void* d_ws, size_t ws_size,
                              hipStream_t stream) {
    const float* slot = (const float*)d_in[0];
    const float* fq   = (const float*)d_in[1];
    const float* ipw  = (const float*)d_in[2];
    const float* ipb  = (const float*)d_in[3];
    const float* opw  = (const float*)d_in[4];
    const float* opb  = (const float*)d_in[5];
    const float* lnqg = (const float*)d_in[6];
    const float* lnqb = (const float*)d_in[7];
    const float* lnkg = (const float*)d_in[8];
    const float* lnkb = (const float*)d_in[9];
    const float* wih  = (const float*)d_in[10];
    const float* whh  = (const float*)d_in[11];
    const float* bihp = (const float*)d_in[12];
    const float* bhhp = (const float*)d_in[13];
    const float* sigr = (const float*)d_in[14];
    const float* praw = (const float*)d_in[15];
    const float* p1w  = (const float*)d_in[16];
    const float* p1b  = (const float*)d_in[17];
    const float* p2w  = (const float*)d_in[18];
    const float* p2b  = (const float*)d_in[19];
    const int M = in_sizes[0] / (NS*DM);   // 65536
    fusion_kernel<<<dim3(256), dim3(NTHR), 0, stream>>>(
        slot, fq, ipw, ipb, opw, opb, lnqg, lnqb, lnkg, lnkb,
        wih, whh, bihp, bhhp, sigr, praw, p1w, p1b, p2w, p2b,
        (float*)d_out, M);
}